// Round 1
// baseline (1838.204 us; speedup 1.0000x reference)
//
#include <hip/hip_runtime.h>

#define N_TOK 262144
#define LATD  128
#define DIMD  256

// ---------------- workspace layout (32-bit word offsets) ----------------
#define W_MT_SYN   0         // 256x128 f32 transposed [cb_syn^T | W_syn]
#define W_MT_SEM   32768     // 256x256 f32 transposed [cb_sem^T | W_sem]
#define W_CBN_SYN  98304     // 64  f32 ||cb||^2
#define W_CBN_SEM  98368     // 128 f32
#define W_IDX_SYN  98496     // 262144 i32
#define W_IDX_SEM  360640    // 262144 i32
#define W_CNT_SYN  622784    // 64  i32
#define W_CNT_SEM  622848    // 128 i32
#define W_EMB_SYN  622976    // 64x256 f32
#define W_EMB_SEM  639360    // 128x256 f32
#define W_MRK_SYN  672128    // 64x64 i32
#define W_MRK_SEM  676224    // 128x128 i32
#define W_SSQ_SYN  692608    // f32
#define W_SSQ_SEM  692609    // f32
#define W_N_SYN    692610    // f32
#define W_N_SEM    692611    // f32
#define W_ZERO_BEG 622784
#define W_ZERO_END 692612

// ---------------- output layout (float offsets) ----------------
#define OFF_ZQ_SYN  0LL
#define OFF_ZQ_SEM  67108864LL
#define OFF_LOSS    134217728LL
#define OFF_IDX_SYN 134217729LL
#define OFF_IDX_SEM 134479873LL
#define OFF_CB_SYN  134742017LL
#define OFF_CL_SYN  134758401LL
#define OFF_AVG_SYN 134758465LL
#define OFF_ADJ_SYN 134774849LL
#define OFF_CB_SEM  134778945LL
#define OFF_CL_SEM  134811713LL
#define OFF_AVG_SEM 134811841LL
#define OFF_ADJ_SEM 134844609LL

__global__ __launch_bounds__(256) void k_init(float* __restrict__ ws) {
  int idx = W_ZERO_BEG + blockIdx.x * 256 + threadIdx.x;
  if (idx < W_ZERO_END) ws[idx] = 0.0f;
}

// Build Mt[j][r]: r<K -> cb[r][j]; r>=K -> W[j][r-K].  grid 256x256 covers 65536.
__global__ __launch_bounds__(256) void k_prep_mt(
    const float* __restrict__ cbs, const float* __restrict__ cbm,
    const float* __restrict__ Wsy, const float* __restrict__ Wse,
    float* __restrict__ ws) {
  int e = blockIdx.x * 256 + threadIdx.x;
  if (e < 32768) {
    int j = e >> 7, r = e & 127;
    ws[W_MT_SYN + e] = (r < 64) ? cbs[r * DIMD + j] : Wsy[j * 64 + (r - 64)];
  }
  {
    int j = e >> 8, r = e & 255;
    ws[W_MT_SEM + e] = (r < 128) ? cbm[r * DIMD + j] : Wse[j * 128 + (r - 128)];
  }
}

// ||cb_k||^2.  grid = 192 blocks (64 syn + 128 sem), 256 threads.
__global__ __launch_bounds__(256) void k_prep_norm(
    const float* __restrict__ cbs, const float* __restrict__ cbm,
    float* __restrict__ ws) {
  __shared__ float red[256];
  int k = blockIdx.x;
  const float* src;
  float* dst;
  if (k < 64) { src = cbs + (size_t)k * DIMD; dst = ws + W_CBN_SYN + k; }
  else        { src = cbm + (size_t)(k - 64) * DIMD; dst = ws + W_CBN_SEM + (k - 64); }
  float v = src[threadIdx.x];
  red[threadIdx.x] = v * v;
  __syncthreads();
  for (int s = 128; s > 0; s >>= 1) {
    if (threadIdx.x < s) red[threadIdx.x] += red[threadIdx.x + s];
    __syncthreads();
  }
  if (threadIdx.x == 0) *dst = red[0];
}

// ---- pass A: per-token GEMM (distances + logits), softmax, argmin, zq ----
template <int K>
__global__ __launch_bounds__(256) void k_passA(
    const float* __restrict__ zre, const float* __restrict__ zim,
    const float* __restrict__ Mt,  const float* __restrict__ cbn,
    const float* __restrict__ cb,  const float* __restrict__ bvec,
    const float* __restrict__ adj, const int* __restrict__ prev,
    float* __restrict__ zq_out, float* __restrict__ idxf_out,
    int* __restrict__ idxi_ws, int* __restrict__ mark_ws) {
  constexpr int R   = 2 * K;      // 128 or 256
  constexpr int RPT = R / 32;     // 4 or 8 columns per thread
  constexpr int TB  = 32;         // tokens per block
  constexpr int LP  = 260;        // padded zf row stride (16B-aligned, bank-spread)
  __shared__ float lds[TB * LP];  // 33.3 KB; reused for S tile (needs TB*R <= TB*LP)

  const int tid = threadIdx.x;
  const int t0  = blockIdx.x * TB;

  // stage zf tile: lds[t][j] = concat(re,im), coalesced float4 loads
  {
    const float4* re4 = (const float4*)(zre + (size_t)t0 * LATD);
    const float4* im4 = (const float4*)(zim + (size_t)t0 * LATD);
#pragma unroll
    for (int it = 0; it < 8; ++it) {
      int v = tid + 256 * it;      // 0..2047 float4s
      int t = v >> 6;
      int c = v & 63;
      float4 x = (c < 32) ? re4[t * 32 + c] : im4[t * 32 + (c - 32)];
      *(float4*)&lds[t * LP + c * 4] = x;
    }
  }
  __syncthreads();

  const int rg = tid & 31;   // column group
  const int tg = tid >> 5;   // token group (8 groups x 4 tokens)
  float acc[4][RPT];
#pragma unroll
  for (int i = 0; i < 4; ++i)
#pragma unroll
    for (int q = 0; q < RPT; ++q) acc[i][q] = 0.0f;

  const float4* Mt4 = (const float4*)Mt;
#pragma unroll 4
  for (int j = 0; j < DIMD; ++j) {
    float a0 = lds[(tg * 4 + 0) * LP + j];
    float a1 = lds[(tg * 4 + 1) * LP + j];
    float a2 = lds[(tg * 4 + 2) * LP + j];
    float a3 = lds[(tg * 4 + 3) * LP + j];
#pragma unroll
    for (int q = 0; q < RPT / 4; ++q) {
      float4 m = Mt4[(size_t)j * (R / 4) + rg * (RPT / 4) + q];
      acc[0][4 * q + 0] += a0 * m.x; acc[0][4 * q + 1] += a0 * m.y;
      acc[0][4 * q + 2] += a0 * m.z; acc[0][4 * q + 3] += a0 * m.w;
      acc[1][4 * q + 0] += a1 * m.x; acc[1][4 * q + 1] += a1 * m.y;
      acc[1][4 * q + 2] += a1 * m.z; acc[1][4 * q + 3] += a1 * m.w;
      acc[2][4 * q + 0] += a2 * m.x; acc[2][4 * q + 1] += a2 * m.y;
      acc[2][4 * q + 2] += a2 * m.z; acc[2][4 * q + 3] += a2 * m.w;
      acc[3][4 * q + 0] += a3 * m.x; acc[3][4 * q + 1] += a3 * m.y;
      acc[3][4 * q + 2] += a3 * m.z; acc[3][4 * q + 3] += a3 * m.w;
    }
  }
  __syncthreads();

  // dump S tile [TB][R] into (reused) LDS
  float* S = lds;
#pragma unroll
  for (int i = 0; i < 4; ++i) {
    int t = tg * 4 + i;
#pragma unroll
    for (int q = 0; q < RPT / 4; ++q) {
      float4 v = make_float4(acc[i][4 * q + 0], acc[i][4 * q + 1],
                             acc[i][4 * q + 2], acc[i][4 * q + 3]);
      *(float4*)&S[t * R + rg * RPT + q * 4] = v;
    }
  }
  __syncthreads();

  // epilogue: one wave per token
  const int wave = tid >> 6, lane = tid & 63;
  const float4* cb4 = (const float4*)cb;
  float4* zq4 = (float4*)zq_out;
  for (int t = wave; t < TB; t += 4) {
    const int gt = t0 + t;
    const int pv = prev[gt];
    float bv; int bi;
    if (K == 64) {
      float lg = S[t * R + 64 + lane] + bvec[lane];
      float mx = lg;
#pragma unroll
      for (int off = 32; off; off >>= 1) mx = fmaxf(mx, __shfl_xor(mx, off));
      float e = __expf(lg - mx);
      float es = e;
#pragma unroll
      for (int off = 32; off; off >>= 1) es += __shfl_xor(es, off);
      float p  = e / es;
      float av = adj[pv * 64 + lane];
      float sg = 1.0f / (1.0f + __expf(-av));
      bv = cbn[lane] - 2.0f * S[t * R + lane] - 0.8f * sg - 2.0f * p;
      bi = lane;
    } else {
      float lg0 = S[t * R + 128 + lane] + bvec[lane];
      float lg1 = S[t * R + 192 + lane] + bvec[lane + 64];
      float mx = fmaxf(lg0, lg1);
#pragma unroll
      for (int off = 32; off; off >>= 1) mx = fmaxf(mx, __shfl_xor(mx, off));
      float e0 = __expf(lg0 - mx), e1 = __expf(lg1 - mx);
      float es = e0 + e1;
#pragma unroll
      for (int off = 32; off; off >>= 1) es += __shfl_xor(es, off);
      float a0 = adj[pv * 128 + lane], a1 = adj[pv * 128 + 64 + lane];
      float s0 = 1.0f / (1.0f + __expf(-a0));
      float s1 = 1.0f / (1.0f + __expf(-a1));
      float dv0 = cbn[lane]      - 2.0f * S[t * R + lane]      - 0.8f * s0 - 2.0f * (e0 / es);
      float dv1 = cbn[lane + 64] - 2.0f * S[t * R + 64 + lane] - 0.8f * s1 - 2.0f * (e1 / es);
      bv = dv0; bi = lane;
      if (dv1 < dv0) { bv = dv1; bi = lane + 64; }
    }
#pragma unroll
    for (int off = 32; off; off >>= 1) {
      float ov = __shfl_xor(bv, off);
      int   oi = __shfl_xor(bi, off);
      if (ov < bv || (ov == bv && oi < bi)) { bv = ov; bi = oi; }
    }
    if (lane == 0) {
      idxf_out[gt] = (float)bi;
      idxi_ws[gt]  = bi;
      mark_ws[pv * K + bi] = 1;   // all duplicate writers store 1 -> deterministic
    }
    zq4[(size_t)gt * 64 + lane] = cb4[(size_t)bi * 64 + lane];
  }
}

// ---- pass B: counts / embed sums / loss via LDS histograms ----
// grid = 1024: blockIdx = chunk*4 + quarter.  Each quarter handles 64 of the 256 cols.
template <int K>
__global__ __launch_bounds__(256) void k_passB(
    const float* __restrict__ zre, const float* __restrict__ zim,
    const float* __restrict__ cb,  const int* __restrict__ idxi,
    float* __restrict__ emb_ws, int* __restrict__ cnt_ws, float* __restrict__ ssq_ws) {
  __shared__ float eml[K * 64];
  __shared__ int   cntl[K];
  __shared__ float wred[4];
  const int tid   = threadIdx.x;
  const int qtr   = blockIdx.x & 3;
  const int chunk = blockIdx.x >> 2;   // 0..255
  for (int e = tid; e < K * 64; e += 256) eml[e] = 0.0f;
  if (tid < K) cntl[tid] = 0;
  __syncthreads();
  const int wave = tid >> 6, lane = tid & 63;
  const float* zsrc = (qtr < 2) ? zre : zim;
  const int jloc  = (qtr & 1) * 64;
  const int jglob = qtr * 64;
  float lacc = 0.0f;
  const int tbeg = chunk * (N_TOK / 256);
  for (int t = tbeg + wave; t < tbeg + N_TOK / 256; t += 4) {
    int id  = idxi[t];
    float z = zsrc[(size_t)t * LATD + jloc + lane];
    atomicAdd(&eml[id * 64 + lane], z);
    if (qtr == 0 && lane == 0) atomicAdd(&cntl[id], 1);
    float d = cb[(size_t)id * DIMD + jglob + lane] - z;
    lacc += d * d;
  }
  __syncthreads();
  for (int e = tid; e < K * 64; e += 256) {
    int k = e >> 6, j = e & 63;
    atomicAdd(&emb_ws[k * DIMD + jglob + j], eml[e]);
  }
  if (qtr == 0)
    for (int e = tid; e < K; e += 256) atomicAdd(&cnt_ws[e], cntl[e]);
#pragma unroll
  for (int off = 32; off; off >>= 1) lacc += __shfl_xor(lacc, off);
  if (lane == 0) wred[wave] = lacc;
  __syncthreads();
  if (tid == 0) atomicAdd(ssq_ws, wred[0] + wred[1] + wred[2] + wred[3]);
}

// ---- finalize 1: cl_new, n sums, loss ----
__global__ __launch_bounds__(256) void k_fin1(
    float* __restrict__ ws, const float* __restrict__ clsi, const float* __restrict__ clmi,
    float* __restrict__ out_cl_syn, float* __restrict__ out_cl_sem, float* __restrict__ out_loss) {
  __shared__ float s1[64], s2[128];
  const int* wsi = (const int*)ws;
  int tid = threadIdx.x;
  if (tid < 64) {
    float c  = (float)wsi[W_CNT_SYN + tid];
    float cl = clsi[tid] * 0.99f + 0.01f * c;
    out_cl_syn[tid] = cl; s1[tid] = cl;
  }
  if (tid < 128) {
    float c  = (float)wsi[W_CNT_SEM + tid];
    float cl = clmi[tid] * 0.99f + 0.01f * c;
    out_cl_sem[tid] = cl; s2[tid] = cl;
  }
  __syncthreads();
  if (tid == 0) {
    float n1 = 0.0f; for (int i = 0; i < 64;  ++i) n1 += s1[i];
    float n2 = 0.0f; for (int i = 0; i < 128; ++i) n2 += s2[i];
    ws[W_N_SYN] = n1;
    ws[W_N_SEM] = n2;
    float denom = (float)N_TOK * 256.0f;
    *out_loss = 1.25f * (ws[W_SSQ_SYN] + ws[W_SSQ_SEM]) / denom;
  }
}

// ---- finalize 2: avg_new, cb_new, adj_new ----
__global__ __launch_bounds__(256) void k_fin2(
    const float* __restrict__ ws,
    const float* __restrict__ avgs, const float* __restrict__ avgm,
    const float* __restrict__ adjs, const float* __restrict__ adjm,
    const float* __restrict__ clsi, const float* __restrict__ clmi,
    float* __restrict__ o_cb_syn, float* __restrict__ o_avg_syn, float* __restrict__ o_adj_syn,
    float* __restrict__ o_cb_sem, float* __restrict__ o_avg_sem, float* __restrict__ o_adj_sem) {
  const int* wsi = (const int*)ws;
  int e = blockIdx.x * 256 + threadIdx.x;
  if (e < 16384) {                       // syn avg/cb
    int k = e >> 8;
    float av = avgs[e] * 0.99f + 0.01f * ws[W_EMB_SYN + e];
    o_avg_syn[e] = av;
    float cnt = (float)wsi[W_CNT_SYN + k];
    float cl  = clsi[k] * 0.99f + 0.01f * cnt;
    float n   = ws[W_N_SYN];
    float cs  = (cl + 1e-6f) / (n + (float)(64 * 1e-6)) * n;
    o_cb_syn[e] = av / cs;
  } else if (e < 49152) {                // sem avg/cb
    int e2 = e - 16384;
    int k = e2 >> 8;
    float av = avgm[e2] * 0.99f + 0.01f * ws[W_EMB_SEM + e2];
    o_avg_sem[e2] = av;
    float cnt = (float)wsi[W_CNT_SEM + k];
    float cl  = clmi[k] * 0.99f + 0.01f * cnt;
    float n   = ws[W_N_SEM];
    float cs  = (cl + 1e-6f) / (n + (float)(128 * 1e-6)) * n;
    o_cb_sem[e2] = av / cs;
  } else if (e < 53248) {                // adj syn
    int a = e - 49152;
    float old = adjs[a];
    o_adj_syn[a] = wsi[W_MRK_SYN + a] ? old * 0.995f + 1.0f : old;
  } else if (e < 69632) {                // adj sem
    int a = e - 53248;
    float old = adjm[a];
    o_adj_sem[a] = wsi[W_MRK_SEM + a] ? old * 0.995f + 1.0f : old;
  }
}

extern "C" void kernel_launch(void* const* d_in, const int* in_sizes, int n_in,
                              void* d_out, int out_size, void* d_ws, size_t ws_size,
                              hipStream_t stream) {
  const float* zfre = (const float*)d_in[0];
  const float* zfim = (const float*)d_in[1];
  const float* zsre = (const float*)d_in[2];
  const float* zsim = (const float*)d_in[3];
  const float* cbs  = (const float*)d_in[4];
  const float* cbm  = (const float*)d_in[5];
  const float* Wsy  = (const float*)d_in[6];
  const float* bsy  = (const float*)d_in[7];
  const float* Wse  = (const float*)d_in[8];
  const float* bse  = (const float*)d_in[9];
  const float* clsi = (const float*)d_in[10];
  const float* avgs = (const float*)d_in[11];
  const float* clmi = (const float*)d_in[12];
  const float* avgm = (const float*)d_in[13];
  const float* adjs = (const float*)d_in[14];
  const float* adjm = (const float*)d_in[15];
  const int*   prvs = (const int*)d_in[16];
  const int*   prvm = (const int*)d_in[17];

  float* out = (float*)d_out;
  float* wsf = (float*)d_ws;
  int*   wsi = (int*)d_ws;

  k_init<<<(W_ZERO_END - W_ZERO_BEG + 255) / 256, 256, 0, stream>>>(wsf);
  k_prep_mt<<<256, 256, 0, stream>>>(cbs, cbm, Wsy, Wse, wsf);
  k_prep_norm<<<192, 256, 0, stream>>>(cbs, cbm, wsf);

  k_passA<64><<<N_TOK / 32, 256, 0, stream>>>(
      zfre, zfim, wsf + W_MT_SYN, wsf + W_CBN_SYN, cbs, bsy, adjs, prvs,
      out + OFF_ZQ_SYN, out + OFF_IDX_SYN, wsi + W_IDX_SYN, wsi + W_MRK_SYN);
  k_passA<128><<<N_TOK / 32, 256, 0, stream>>>(
      zsre, zsim, wsf + W_MT_SEM, wsf + W_CBN_SEM, cbm, bse, adjm, prvm,
      out + OFF_ZQ_SEM, out + OFF_IDX_SEM, wsi + W_IDX_SEM, wsi + W_MRK_SEM);

  k_passB<64><<<1024, 256, 0, stream>>>(
      zfre, zfim, cbs, wsi + W_IDX_SYN, wsf + W_EMB_SYN, wsi + W_CNT_SYN, wsf + W_SSQ_SYN);
  k_passB<128><<<1024, 256, 0, stream>>>(
      zsre, zsim, cbm, wsi + W_IDX_SEM, wsf + W_EMB_SEM, wsi + W_CNT_SEM, wsf + W_SSQ_SEM);

  k_fin1<<<1, 256, 0, stream>>>(wsf, clsi, clmi,
      out + OFF_CL_SYN, out + OFF_CL_SEM, out + OFF_LOSS);
  k_fin2<<<272, 256, 0, stream>>>(wsf, avgs, avgm, adjs, adjm, clsi, clmi,
      out + OFF_CB_SYN, out + OFF_AVG_SYN, out + OFF_ADJ_SYN,
      out + OFF_CB_SEM, out + OFF_AVG_SEM, out + OFF_ADJ_SEM);
}

// Round 2
// 1343.415 us; speedup vs baseline: 1.3683x; 1.3683x over previous
//
#include <hip/hip_runtime.h>

#define N_TOK 262144
#define LATD  128
#define DIMD  256

using f32x4  = __attribute__((ext_vector_type(4)))  float;
using f32x16 = __attribute__((ext_vector_type(16))) float;
using f16x8  = __attribute__((ext_vector_type(8)))  _Float16;

// ---------------- workspace layout (32-bit word offsets) ----------------
#define W_PACK_SYN 0         // 65536 f16 (32768 words): [kt][hi/lo][ct][lane][e]
#define W_PACK_SEM 32768     // 131072 f16 (65536 words)
#define W_CBN_SYN  98304     // 64  f32 ||cb||^2
#define W_CBN_SEM  98368     // 128 f32
#define W_IDX_SYN  98496     // 262144 i32
#define W_IDX_SEM  360640    // 262144 i32
#define W_CNT_SYN  622784    // 64  i32
#define W_CNT_SEM  622848    // 128 i32
#define W_EMB_SYN  622976    // 64x256 f32
#define W_EMB_SEM  639360    // 128x256 f32
#define W_MRK_SYN  672128    // 64x64 i32
#define W_MRK_SEM  676224    // 128x128 i32
#define W_SSQ_SYN  692608    // f32
#define W_SSQ_SEM  692609    // f32
#define W_N_SYN    692610    // f32
#define W_N_SEM    692611    // f32
#define W_ZERO_BEG 622784
#define W_ZERO_END 692612

// ---------------- output layout (float offsets) ----------------
#define OFF_ZQ_SYN  0LL
#define OFF_ZQ_SEM  67108864LL
#define OFF_LOSS    134217728LL
#define OFF_IDX_SYN 134217729LL
#define OFF_IDX_SEM 134479873LL
#define OFF_CB_SYN  134742017LL
#define OFF_CL_SYN  134758401LL
#define OFF_AVG_SYN 134758465LL
#define OFF_ADJ_SYN 134774849LL
#define OFF_CB_SEM  134778945LL
#define OFF_CL_SEM  134811713LL
#define OFF_AVG_SEM 134811841LL
#define OFF_ADJ_SEM 134844609LL

__device__ inline void gload16(const void* g, void* l) {
  __builtin_amdgcn_global_load_lds(
      (const __attribute__((address_space(1))) unsigned int*)g,
      (__attribute__((address_space(3))) unsigned int*)l, 16, 0, 0);
}

__global__ __launch_bounds__(256) void k_init(float* __restrict__ ws) {
  int idx = W_ZERO_BEG + blockIdx.x * 256 + threadIdx.x;
  if (idx < W_ZERO_END) ws[idx] = 0.0f;
}

// Pack Mt = [cb^T | W] into 32x32x16 f16 fragment order, hi + lo halves.
// Mt[j][r] = r<K ? cb[r][j] : W[j][r-K].  One thread per f16 element pair.
template <int K>
__global__ __launch_bounds__(256) void k_prep_pack(
    const float* __restrict__ cb, const float* __restrict__ W,
    _Float16* __restrict__ pack) {
  constexpr int R   = 2 * K;
  constexpr int NCT = R / 32;
  constexpr int PER_KT = NCT * 512;
  int t = blockIdx.x * 256 + threadIdx.x;   // < 16*PER_KT
  int kt = t / PER_KT;
  int r  = t - kt * PER_KT;
  int ct = r >> 9;
  int l  = (r >> 3) & 63;
  int e  = r & 7;
  int j   = kt * 16 + (l >> 5) * 8 + e;
  int col = ct * 32 + (l & 31);
  float x = (col < K) ? cb[col * DIMD + j] : W[j * K + (col - K)];
  _Float16 h = (_Float16)x;
  _Float16 lo = (_Float16)(x - (float)h);
  pack[(size_t)kt * 2 * PER_KT + r]          = h;
  pack[(size_t)kt * 2 * PER_KT + PER_KT + r] = lo;
}

// ||cb_k||^2.  grid = 192 blocks (64 syn + 128 sem), 256 threads.
__global__ __launch_bounds__(256) void k_prep_norm(
    const float* __restrict__ cbs, const float* __restrict__ cbm,
    float* __restrict__ ws) {
  __shared__ float red[256];
  int k = blockIdx.x;
  const float* src;
  float* dst;
  if (k < 64) { src = cbs + (size_t)k * DIMD; dst = ws + W_CBN_SYN + k; }
  else        { src = cbm + (size_t)(k - 64) * DIMD; dst = ws + W_CBN_SEM + (k - 64); }
  float v = src[threadIdx.x];
  red[threadIdx.x] = v * v;
  __syncthreads();
  for (int s = 128; s > 0; s >>= 1) {
    if (threadIdx.x < s) red[threadIdx.x] += red[threadIdx.x + s];
    __syncthreads();
  }
  if (threadIdx.x == 0) *dst = red[0];
}

// ---- pass A: split-f16 MFMA GEMM (distances + logits), softmax, argmin, zq ----
template <int K>
__global__ __launch_bounds__(256) void k_passA(
    const float* __restrict__ zre, const float* __restrict__ zim,
    const _Float16* __restrict__ pack, const float* __restrict__ cbn,
    const float* __restrict__ cb,  const float* __restrict__ bvec,
    const float* __restrict__ adj, const int* __restrict__ prev,
    float* __restrict__ zq_out, float* __restrict__ idxf_out,
    int* __restrict__ idxi_ws, int* __restrict__ mark_ws) {
  constexpr int R   = 2 * K;           // 128 / 256
  constexpr int NCT = R / 32;          // 4 / 8
  constexpr int TB  = 32;              // tokens per block
  constexpr int NKT = 16;              // k-chunks of 16
  constexpr int PER_KT = NCT * 512;    // f16 per hi (or lo) chunk
  constexpr int BW  = 2 * PER_KT;      // f16 per staged chunk
  constexpr int NACC = NCT / 4;        // col-tiles per wave (1 or 2)
  __shared__ __align__(16) float smem[TB * 256 + BW / 2];  // A f32 tile + B f16 chunk

  const int tid  = threadIdx.x;
  const int lane = tid & 63;
  const int wv   = tid >> 6;
  const int t0   = blockIdx.x * TB;
  _Float16* Bp = (_Float16*)(smem + TB * 256);

  // ---- stage A tile (f32) via global_load_lds, source pre-swizzled ----
  // LDS slot (row, s) holds global float4 index s ^ (row&7) of row's concat(re,im).
#pragma unroll
  for (int it = 0; it < 8; ++it) {
    int off16 = it * 256 + tid;        // 16B slot id, 64 slots per row
    int row = off16 >> 6;
    int s   = off16 & 63;
    int fidx = s ^ (row & 7);
    const float* g = (fidx < 32)
        ? (zre + (((size_t)(t0 + row)) << 7) + fidx * 4)
        : (zim + (((size_t)(t0 + row)) << 7) + (fidx - 32) * 4);
    gload16(g, (char*)smem + ((it * 256 + (tid & 192)) << 4));
  }
  // ---- stage B chunk kt=0 ----
  {
    const _Float16* src = pack;
#pragma unroll
    for (int i = 0; i < BW / 2048; ++i)
      gload16(src + (size_t)(i * 256 + tid) * 8,
              (char*)Bp + ((i * 256 + (tid & 192)) << 4));
  }

  const int row = lane & 31;
  const int kg  = lane >> 5;
  const int ct0 = wv * NACC;
  f32x16 acc[NACC];
#pragma unroll
  for (int c = 0; c < NACC; ++c)
#pragma unroll
    for (int r = 0; r < 16; ++r) acc[c][r] = 0.0f;

  for (int kt = 0; kt < NKT; ++kt) {
    __syncthreads();                   // B(kt) staged (+A on kt=0); prev compute done
    // A fragment: 8 f32 at k = kt*16 + kg*8 .. +7, swizzled slots
    int f0 = kt * 4 + kg * 2;
    f32x4 v0 = *(const f32x4*)&smem[row * 256 + ((f0)     ^ (row & 7)) * 4];
    f32x4 v1 = *(const f32x4*)&smem[row * 256 + ((f0 + 1) ^ (row & 7)) * 4];
    f16x8 Ah, Al;
#pragma unroll
    for (int e = 0; e < 4; ++e) {
      _Float16 h0 = (_Float16)v0[e];
      Ah[e] = h0;       Al[e] = (_Float16)(v0[e] - (float)h0);
      _Float16 h1 = (_Float16)v1[e];
      Ah[e + 4] = h1;   Al[e + 4] = (_Float16)(v1[e] - (float)h1);
    }
#pragma unroll
    for (int c = 0; c < NACC; ++c) {
      int ct = ct0 + c;
      f16x8 Bh = *(const f16x8*)(Bp + ((size_t)(ct) * 64 + lane) * 8);
      f16x8 Bl = *(const f16x8*)(Bp + ((size_t)(NCT + ct) * 64 + lane) * 8);
      acc[c] = __builtin_amdgcn_mfma_f32_32x32x16_f16(Ah, Bh, acc[c], 0, 0, 0);
      acc[c] = __builtin_amdgcn_mfma_f32_32x32x16_f16(Ah, Bl, acc[c], 0, 0, 0);
      acc[c] = __builtin_amdgcn_mfma_f32_32x32x16_f16(Al, Bh, acc[c], 0, 0, 0);
    }
    if (kt + 1 < NKT) {
      __syncthreads();                 // everyone done reading B(kt)
      const _Float16* src = pack + (size_t)(kt + 1) * BW;
#pragma unroll
      for (int i = 0; i < BW / 2048; ++i)
        gload16(src + (size_t)(i * 256 + tid) * 8,
                (char*)Bp + ((i * 256 + (tid & 192)) << 4));
    }
  }
  __syncthreads();                     // compute done; A region reusable as S

  // ---- dump S[32][R] (f32) into A region ----
  float* S = smem;
#pragma unroll
  for (int c = 0; c < NACC; ++c) {
    int col = ct0 * 32 + c * 32 + (lane & 31);
#pragma unroll
    for (int r = 0; r < 16; ++r) {
      int rw = (r & 3) + 8 * (r >> 2) + 4 * kg;
      S[rw * R + col] = acc[c][r];
    }
  }
  __syncthreads();

  // ---- epilogue: one wave per token (verified round-1 logic) ----
  const float4* cb4 = (const float4*)cb;
  float4* zq4 = (float4*)zq_out;
  for (int t = wv; t < TB; t += 4) {
    const int gt = t0 + t;
    const int pv = prev[gt];
    float bv; int bi;
    if (K == 64) {
      float lg = S[t * R + 64 + lane] + bvec[lane];
      float mx = lg;
#pragma unroll
      for (int off = 32; off; off >>= 1) mx = fmaxf(mx, __shfl_xor(mx, off));
      float e = __expf(lg - mx);
      float es = e;
#pragma unroll
      for (int off = 32; off; off >>= 1) es += __shfl_xor(es, off);
      float p  = e / es;
      float av = adj[pv * 64 + lane];
      float sg = 1.0f / (1.0f + __expf(-av));
      bv = cbn[lane] - 2.0f * S[t * R + lane] - 0.8f * sg - 2.0f * p;
      bi = lane;
    } else {
      float lg0 = S[t * R + 128 + lane] + bvec[lane];
      float lg1 = S[t * R + 192 + lane] + bvec[lane + 64];
      float mx = fmaxf(lg0, lg1);
#pragma unroll
      for (int off = 32; off; off >>= 1) mx = fmaxf(mx, __shfl_xor(mx, off));
      float e0 = __expf(lg0 - mx), e1 = __expf(lg1 - mx);
      float es = e0 + e1;
#pragma unroll
      for (int off = 32; off; off >>= 1) es += __shfl_xor(es, off);
      float a0 = adj[pv * 128 + lane], a1 = adj[pv * 128 + 64 + lane];
      float s0 = 1.0f / (1.0f + __expf(-a0));
      float s1 = 1.0f / (1.0f + __expf(-a1));
      float dv0 = cbn[lane]      - 2.0f * S[t * R + lane]      - 0.8f * s0 - 2.0f * (e0 / es);
      float dv1 = cbn[lane + 64] - 2.0f * S[t * R + 64 + lane] - 0.8f * s1 - 2.0f * (e1 / es);
      bv = dv0; bi = lane;
      if (dv1 < dv0) { bv = dv1; bi = lane + 64; }
    }
#pragma unroll
    for (int off = 32; off; off >>= 1) {
      float ov = __shfl_xor(bv, off);
      int   oi = __shfl_xor(bi, off);
      if (ov < bv || (ov == bv && oi < bi)) { bv = ov; bi = oi; }
    }
    if (lane == 0) {
      idxf_out[gt] = (float)bi;
      idxi_ws[gt]  = bi;
      mark_ws[pv * K + bi] = 1;
    }
    zq4[(size_t)gt * 64 + lane] = cb4[(size_t)bi * 64 + lane];
  }
}

// ---- pass B: counts / embed sums / loss via LDS histograms ----
template <int K>
__global__ __launch_bounds__(256) void k_passB(
    const float* __restrict__ zre, const float* __restrict__ zim,
    const float* __restrict__ cb,  const int* __restrict__ idxi,
    float* __restrict__ emb_ws, int* __restrict__ cnt_ws, float* __restrict__ ssq_ws) {
  __shared__ float eml[K * 64];
  __shared__ int   cntl[K];
  __shared__ float wred[4];
  const int tid   = threadIdx.x;
  const int qtr   = blockIdx.x & 3;
  const int chunk = blockIdx.x >> 2;   // 0..255
  for (int e = tid; e < K * 64; e += 256) eml[e] = 0.0f;
  if (tid < K) cntl[tid] = 0;
  __syncthreads();
  const int wave = tid >> 6, lane = tid & 63;
  const float* zsrc = (qtr < 2) ? zre : zim;
  const int jloc  = (qtr & 1) * 64;
  const int jglob = qtr * 64;
  float lacc = 0.0f;
  const int tbeg = chunk * (N_TOK / 256);
  for (int t = tbeg + wave; t < tbeg + N_TOK / 256; t += 4) {
    int id  = idxi[t];
    float z = zsrc[(size_t)t * LATD + jloc + lane];
    atomicAdd(&eml[id * 64 + lane], z);
    if (qtr == 0 && lane == 0) atomicAdd(&cntl[id], 1);
    float d = cb[(size_t)id * DIMD + jglob + lane] - z;
    lacc += d * d;
  }
  __syncthreads();
  for (int e = tid; e < K * 64; e += 256) {
    int k = e >> 6, j = e & 63;
    atomicAdd(&emb_ws[k * DIMD + jglob + j], eml[e]);
  }
  if (qtr == 0)
    for (int e = tid; e < K; e += 256) atomicAdd(&cnt_ws[e], cntl[e]);
#pragma unroll
  for (int off = 32; off; off >>= 1) lacc += __shfl_xor(lacc, off);
  if (lane == 0) wred[wave] = lacc;
  __syncthreads();
  if (tid == 0) atomicAdd(ssq_ws, wred[0] + wred[1] + wred[2] + wred[3]);
}

// ---- finalize 1: cl_new, n sums, loss ----
__global__ __launch_bounds__(256) void k_fin1(
    float* __restrict__ ws, const float* __restrict__ clsi, const float* __restrict__ clmi,
    float* __restrict__ out_cl_syn, float* __restrict__ out_cl_sem, float* __restrict__ out_loss) {
  __shared__ float s1[64], s2[128];
  const int* wsi = (const int*)ws;
  int tid = threadIdx.x;
  if (tid < 64) {
    float c  = (float)wsi[W_CNT_SYN + tid];
    float cl = clsi[tid] * 0.99f + 0.01f * c;
    out_cl_syn[tid] = cl; s1[tid] = cl;
  }
  if (tid < 128) {
    float c  = (float)wsi[W_CNT_SEM + tid];
    float cl = clmi[tid] * 0.99f + 0.01f * c;
    out_cl_sem[tid] = cl; s2[tid] = cl;
  }
  __syncthreads();
  if (tid == 0) {
    float n1 = 0.0f; for (int i = 0; i < 64;  ++i) n1 += s1[i];
    float n2 = 0.0f; for (int i = 0; i < 128; ++i) n2 += s2[i];
    ws[W_N_SYN] = n1;
    ws[W_N_SEM] = n2;
    float denom = (float)N_TOK * 256.0f;
    *out_loss = 1.25f * (ws[W_SSQ_SYN] + ws[W_SSQ_SEM]) / denom;
  }
}

// ---- finalize 2: avg_new, cb_new, adj_new ----
__global__ __launch_bounds__(256) void k_fin2(
    const float* __restrict__ ws,
    const float* __restrict__ avgs, const float* __restrict__ avgm,
    const float* __restrict__ adjs, const float* __restrict__ adjm,
    const float* __restrict__ clsi, const float* __restrict__ clmi,
    float* __restrict__ o_cb_syn, float* __restrict__ o_avg_syn, float* __restrict__ o_adj_syn,
    float* __restrict__ o_cb_sem, float* __restrict__ o_avg_sem, float* __restrict__ o_adj_sem) {
  const int* wsi = (const int*)ws;
  int e = blockIdx.x * 256 + threadIdx.x;
  if (e < 16384) {                       // syn avg/cb
    int k = e >> 8;
    float av = avgs[e] * 0.99f + 0.01f * ws[W_EMB_SYN + e];
    o_avg_syn[e] = av;
    float cnt = (float)wsi[W_CNT_SYN + k];
    float cl  = clsi[k] * 0.99f + 0.01f * cnt;
    float n   = ws[W_N_SYN];
    float cs  = (cl + 1e-6f) / (n + (float)(64 * 1e-6)) * n;
    o_cb_syn[e] = av / cs;
  } else if (e < 49152) {                // sem avg/cb
    int e2 = e - 16384;
    int k = e2 >> 8;
    float av = avgm[e2] * 0.99f + 0.01f * ws[W_EMB_SEM + e2];
    o_avg_sem[e2] = av;
    float cnt = (float)wsi[W_CNT_SEM + k];
    float cl  = clmi[k] * 0.99f + 0.01f * cnt;
    float n   = ws[W_N_SEM];
    float cs  = (cl + 1e-6f) / (n + (float)(128 * 1e-6)) * n;
    o_cb_sem[e2] = av / cs;
  } else if (e < 53248) {                // adj syn
    int a = e - 49152;
    float old = adjs[a];
    o_adj_syn[a] = wsi[W_MRK_SYN + a] ? old * 0.995f + 1.0f : old;
  } else if (e < 69632) {                // adj sem
    int a = e - 53248;
    float old = adjm[a];
    o_adj_sem[a] = wsi[W_MRK_SEM + a] ? old * 0.995f + 1.0f : old;
  }
}

extern "C" void kernel_launch(void* const* d_in, const int* in_sizes, int n_in,
                              void* d_out, int out_size, void* d_ws, size_t ws_size,
                              hipStream_t stream) {
  const float* zfre = (const float*)d_in[0];
  const float* zfim = (const float*)d_in[1];
  const float* zsre = (const float*)d_in[2];
  const float* zsim = (const float*)d_in[3];
  const float* cbs  = (const float*)d_in[4];
  const float* cbm  = (const float*)d_in[5];
  const float* Wsy  = (const float*)d_in[6];
  const float* bsy  = (const float*)d_in[7];
  const float* Wse  = (const float*)d_in[8];
  const float* bse  = (const float*)d_in[9];
  const float* clsi = (const float*)d_in[10];
  const float* avgs = (const float*)d_in[11];
  const float* clmi = (const float*)d_in[12];
  const float* avgm = (const float*)d_in[13];
  const float* adjs = (const float*)d_in[14];
  const float* adjm = (const float*)d_in[15];
  const int*   prvs = (const int*)d_in[16];
  const int*   prvm = (const int*)d_in[17];

  float* out = (float*)d_out;
  float* wsf = (float*)d_ws;
  int*   wsi = (int*)d_ws;
  _Float16* wsh = (_Float16*)d_ws;

  k_init<<<(W_ZERO_END - W_ZERO_BEG + 255) / 256, 256, 0, stream>>>(wsf);
  k_prep_pack<64><<<128, 256, 0, stream>>>(cbs, Wsy, wsh + 2 * W_PACK_SYN);
  k_prep_pack<128><<<256, 256, 0, stream>>>(cbm, Wse, wsh + 2 * W_PACK_SEM);
  k_prep_norm<<<192, 256, 0, stream>>>(cbs, cbm, wsf);

  k_passA<64><<<N_TOK / 32, 256, 0, stream>>>(
      zfre, zfim, wsh + 2 * W_PACK_SYN, wsf + W_CBN_SYN, cbs, bsy, adjs, prvs,
      out + OFF_ZQ_SYN, out + OFF_IDX_SYN, wsi + W_IDX_SYN, wsi + W_MRK_SYN);
  k_passA<128><<<N_TOK / 32, 256, 0, stream>>>(
      zsre, zsim, wsh + 2 * W_PACK_SEM, wsf + W_CBN_SEM, cbm, bse, adjm, prvm,
      out + OFF_ZQ_SEM, out + OFF_IDX_SEM, wsi + W_IDX_SEM, wsi + W_MRK_SEM);

  k_passB<64><<<1024, 256, 0, stream>>>(
      zfre, zfim, cbs, wsi + W_IDX_SYN, wsf + W_EMB_SYN, wsi + W_CNT_SYN, wsf + W_SSQ_SYN);
  k_passB<128><<<1024, 256, 0, stream>>>(
      zsre, zsim, cbm, wsi + W_IDX_SEM, wsf + W_EMB_SEM, wsi + W_CNT_SEM, wsf + W_SSQ_SEM);

  k_fin1<<<1, 256, 0, stream>>>(wsf, clsi, clmi,
      out + OFF_CL_SYN, out + OFF_CL_SEM, out + OFF_LOSS);
  k_fin2<<<272, 256, 0, stream>>>(wsf, avgs, avgm, adjs, adjm, clsi, clmi,
      out + OFF_CB_SYN, out + OFF_AVG_SYN, out + OFF_ADJ_SYN,
      out + OFF_CB_SEM, out + OFF_AVG_SEM, out + OFF_ADJ_SEM);
}

// Round 3
// 1239.862 us; speedup vs baseline: 1.4826x; 1.0835x over previous
//
#include <hip/hip_runtime.h>

#define N_TOK 262144
#define LATD  128
#define DIMD  256

using f32x4  = __attribute__((ext_vector_type(4)))  float;
using f32x16 = __attribute__((ext_vector_type(16))) float;
using f16x8  = __attribute__((ext_vector_type(8)))  _Float16;

// ---------------- workspace layout (32-bit word offsets) ----------------
#define W_PACK_SYN 0         // 65536 f16 (32768 words): [kt][hi/lo][ct][lane][e]
#define W_PACK_SEM 32768     // 131072 f16 (65536 words)
#define W_CBN_SYN  98304     // 64  f32 ||cb||^2
#define W_CBN_SEM  98368     // 128 f32
#define W_IDX_SYN  98496     // 262144 i32
#define W_IDX_SEM  360640    // 262144 i32
#define W_CNT_SYN  622784    // 64  i32
#define W_CNT_SEM  622848    // 128 i32
#define W_EMB_SYN  622976    // 64x256 f32
#define W_EMB_SEM  639360    // 128x256 f32
#define W_MRK_SYN  672128    // 64x64 i32
#define W_MRK_SEM  676224    // 128x128 i32
#define W_N_SYN    692610    // f32
#define W_N_SEM    692611    // f32
#define W_LOSSP_SYN 692612   // 8192 f32 per-block loss partials
#define W_LOSSP_SEM 700804   // 8192 f32
#define W_ZERO_BEG 622784
#define W_ZERO_END 692612

// ---------------- output layout (float offsets) ----------------
#define OFF_ZQ_SYN  0LL
#define OFF_ZQ_SEM  67108864LL
#define OFF_LOSS    134217728LL
#define OFF_IDX_SYN 134217729LL
#define OFF_IDX_SEM 134479873LL
#define OFF_CB_SYN  134742017LL
#define OFF_CL_SYN  134758401LL
#define OFF_AVG_SYN 134758465LL
#define OFF_ADJ_SYN 134774849LL
#define OFF_CB_SEM  134778945LL
#define OFF_CL_SEM  134811713LL
#define OFF_AVG_SEM 134811841LL
#define OFF_ADJ_SEM 134844609LL

__device__ inline void gload16(const void* g, void* l) {
  __builtin_amdgcn_global_load_lds(
      (const __attribute__((address_space(1))) unsigned int*)g,
      (__attribute__((address_space(3))) unsigned int*)l, 16, 0, 0);
}

__global__ __launch_bounds__(256) void k_init(float* __restrict__ ws) {
  int idx = W_ZERO_BEG + blockIdx.x * 256 + threadIdx.x;
  if (idx < W_ZERO_END) ws[idx] = 0.0f;
}

// Pack Mt = [cb^T | W] into 32x32x16 f16 fragment order, hi + lo halves.
template <int K>
__global__ __launch_bounds__(256) void k_prep_pack(
    const float* __restrict__ cb, const float* __restrict__ W,
    _Float16* __restrict__ pack) {
  constexpr int R   = 2 * K;
  constexpr int NCT = R / 32;
  constexpr int PER_KT = NCT * 512;
  int t = blockIdx.x * 256 + threadIdx.x;   // < 16*PER_KT
  int kt = t / PER_KT;
  int r  = t - kt * PER_KT;
  int ct = r >> 9;
  int l  = (r >> 3) & 63;
  int e  = r & 7;
  int j   = kt * 16 + (l >> 5) * 8 + e;
  int col = ct * 32 + (l & 31);
  float x = (col < K) ? cb[col * DIMD + j] : W[j * K + (col - K)];
  _Float16 h = (_Float16)x;
  _Float16 lo = (_Float16)(x - (float)h);
  pack[(size_t)kt * 2 * PER_KT + r]          = h;
  pack[(size_t)kt * 2 * PER_KT + PER_KT + r] = lo;
}

// ||cb_k||^2.  grid = 192 blocks (64 syn + 128 sem), 256 threads.
__global__ __launch_bounds__(256) void k_prep_norm(
    const float* __restrict__ cbs, const float* __restrict__ cbm,
    float* __restrict__ ws) {
  __shared__ float red[256];
  int k = blockIdx.x;
  const float* src;
  float* dst;
  if (k < 64) { src = cbs + (size_t)k * DIMD; dst = ws + W_CBN_SYN + k; }
  else        { src = cbm + (size_t)(k - 64) * DIMD; dst = ws + W_CBN_SEM + (k - 64); }
  float v = src[threadIdx.x];
  red[threadIdx.x] = v * v;
  __syncthreads();
  for (int s = 128; s > 0; s >>= 1) {
    if (threadIdx.x < s) red[threadIdx.x] += red[threadIdx.x + s];
    __syncthreads();
  }
  if (threadIdx.x == 0) *dst = red[0];
}

// ---- pass A: split-f16 MFMA GEMM + softmax/argmin/zq + loss partials ----
template <int K>
__global__ __launch_bounds__(256) void k_passA(
    const float* __restrict__ zre, const float* __restrict__ zim,
    const _Float16* __restrict__ pack, const float* __restrict__ cbn,
    const float* __restrict__ cb,  const float* __restrict__ bvec,
    const float* __restrict__ adj, const int* __restrict__ prev,
    float* __restrict__ zq_out, float* __restrict__ idxf_out,
    int* __restrict__ idxi_ws, int* __restrict__ mark_ws,
    float* __restrict__ lossp) {
  constexpr int R   = 2 * K;           // 128 / 256
  constexpr int NCT = R / 32;          // 4 / 8
  constexpr int TB  = 32;              // tokens per block
  constexpr int NKT = 16;              // k-chunks of 16
  constexpr int PER_KT = NCT * 512;    // f16 per hi (or lo) chunk
  constexpr int BW  = 2 * PER_KT;      // f16 per staged chunk
  constexpr int NACC = NCT / 4;        // col-tiles per wave (1 or 2)
  __shared__ __align__(16) float smem[TB * 256 + BW / 2];  // A f32 tile + B f16 chunk
  __shared__ float znl[TB];
  __shared__ float wred2[4];

  const int tid  = threadIdx.x;
  const int lane = tid & 63;
  const int wv   = tid >> 6;
  const int t0   = blockIdx.x * TB;
  _Float16* Bp = (_Float16*)(smem + TB * 256);

  // ---- stage A tile (f32) via global_load_lds, source pre-swizzled ----
#pragma unroll
  for (int it = 0; it < 8; ++it) {
    int off16 = it * 256 + tid;        // 16B slot id, 64 slots per row
    int row = off16 >> 6;
    int s   = off16 & 63;
    int fidx = s ^ (row & 7);
    const float* g = (fidx < 32)
        ? (zre + (((size_t)(t0 + row)) << 7) + fidx * 4)
        : (zim + (((size_t)(t0 + row)) << 7) + (fidx - 32) * 4);
    gload16(g, (char*)smem + ((it * 256 + (tid & 192)) << 4));
  }
  // ---- stage B chunk kt=0 ----
  {
    const _Float16* src = pack;
#pragma unroll
    for (int i = 0; i < BW / 2048; ++i)
      gload16(src + (size_t)(i * 256 + tid) * 8,
              (char*)Bp + ((i * 256 + (tid & 192)) << 4));
  }

  const int row = lane & 31;
  const int kg  = lane >> 5;
  const int ct0 = wv * NACC;
  f32x16 acc[NACC];
#pragma unroll
  for (int c = 0; c < NACC; ++c)
#pragma unroll
    for (int r = 0; r < 16; ++r) acc[c][r] = 0.0f;
  float zn = 0.0f;                     // partial ||zf_row||^2 (this lane's k-slices)

  for (int kt = 0; kt < NKT; ++kt) {
    __syncthreads();                   // B(kt) staged (+A on kt=0); prev compute done
    int f0 = kt * 4 + kg * 2;
    f32x4 v0 = *(const f32x4*)&smem[row * 256 + ((f0)     ^ (row & 7)) * 4];
    f32x4 v1 = *(const f32x4*)&smem[row * 256 + ((f0 + 1) ^ (row & 7)) * 4];
    f16x8 Ah, Al;
#pragma unroll
    for (int e = 0; e < 4; ++e) {
      _Float16 h0 = (_Float16)v0[e];
      Ah[e] = h0;       Al[e] = (_Float16)(v0[e] - (float)h0);
      _Float16 h1 = (_Float16)v1[e];
      Ah[e + 4] = h1;   Al[e + 4] = (_Float16)(v1[e] - (float)h1);
      zn += v0[e] * v0[e];
      zn += v1[e] * v1[e];
    }
#pragma unroll
    for (int c = 0; c < NACC; ++c) {
      int ct = ct0 + c;
      f16x8 Bh = *(const f16x8*)(Bp + ((size_t)(ct) * 64 + lane) * 8);
      f16x8 Bl = *(const f16x8*)(Bp + ((size_t)(NCT + ct) * 64 + lane) * 8);
      acc[c] = __builtin_amdgcn_mfma_f32_32x32x16_f16(Ah, Bh, acc[c], 0, 0, 0);
      acc[c] = __builtin_amdgcn_mfma_f32_32x32x16_f16(Ah, Bl, acc[c], 0, 0, 0);
      acc[c] = __builtin_amdgcn_mfma_f32_32x32x16_f16(Al, Bh, acc[c], 0, 0, 0);
    }
    if (kt + 1 < NKT) {
      __syncthreads();                 // everyone done reading B(kt)
      const _Float16* src = pack + (size_t)(kt + 1) * BW;
#pragma unroll
      for (int i = 0; i < BW / 2048; ++i)
        gload16(src + (size_t)(i * 256 + tid) * 8,
                (char*)Bp + ((i * 256 + (tid & 192)) << 4));
    }
  }
  // full ||zf_row||^2: combine the two kg half-sums; wave 0 publishes
  {
    float znt = zn + __shfl_xor(zn, 32);
    if (wv == 0 && lane < 32) znl[lane] = znt;
  }
  __syncthreads();                     // compute done; A region reusable as S

  // ---- dump S[32][R] (f32) into A region ----
  float* S = smem;
#pragma unroll
  for (int c = 0; c < NACC; ++c) {
    int col = ct0 * 32 + c * 32 + (lane & 31);
#pragma unroll
    for (int r = 0; r < 16; ++r) {
      int rw = (r & 3) + 8 * (r >> 2) + 4 * kg;
      S[rw * R + col] = acc[c][r];
    }
  }
  __syncthreads();

  // ---- epilogue: one wave per token ----
  const float4* cb4 = (const float4*)cb;
  float4* zq4 = (float4*)zq_out;
  float lacc = 0.0f;
  for (int t = wv; t < TB; t += 4) {
    const int gt = t0 + t;
    const int pv = prev[gt];
    float bv; int bi;
    if (K == 64) {
      float lg = S[t * R + 64 + lane] + bvec[lane];
      float mx = lg;
#pragma unroll
      for (int off = 32; off; off >>= 1) mx = fmaxf(mx, __shfl_xor(mx, off));
      float e = __expf(lg - mx);
      float es = e;
#pragma unroll
      for (int off = 32; off; off >>= 1) es += __shfl_xor(es, off);
      float p  = e / es;
      float av = adj[pv * 64 + lane];
      float sg = 1.0f / (1.0f + __expf(-av));
      bv = cbn[lane] - 2.0f * S[t * R + lane] - 0.8f * sg - 2.0f * p;
      bi = lane;
    } else {
      float lg0 = S[t * R + 128 + lane] + bvec[lane];
      float lg1 = S[t * R + 192 + lane] + bvec[lane + 64];
      float mx = fmaxf(lg0, lg1);
#pragma unroll
      for (int off = 32; off; off >>= 1) mx = fmaxf(mx, __shfl_xor(mx, off));
      float e0 = __expf(lg0 - mx), e1 = __expf(lg1 - mx);
      float es = e0 + e1;
#pragma unroll
      for (int off = 32; off; off >>= 1) es += __shfl_xor(es, off);
      float a0 = adj[pv * 128 + lane], a1 = adj[pv * 128 + 64 + lane];
      float s0 = 1.0f / (1.0f + __expf(-a0));
      float s1 = 1.0f / (1.0f + __expf(-a1));
      float dv0 = cbn[lane]      - 2.0f * S[t * R + lane]      - 0.8f * s0 - 2.0f * (e0 / es);
      float dv1 = cbn[lane + 64] - 2.0f * S[t * R + 64 + lane] - 0.8f * s1 - 2.0f * (e1 / es);
      bv = dv0; bi = lane;
      if (dv1 < dv0) { bv = dv1; bi = lane + 64; }
    }
#pragma unroll
    for (int off = 32; off; off >>= 1) {
      float ov = __shfl_xor(bv, off);
      int   oi = __shfl_xor(bi, off);
      if (ov < bv || (ov == bv && oi < bi)) { bv = ov; bi = oi; }
    }
    if (lane == 0) {
      idxf_out[gt] = (float)bi;
      idxi_ws[gt]  = bi;
      mark_ws[pv * K + bi] = 1;
      // loss partial: ||cb_bi||^2 - 2*zf.cb_bi + ||zf||^2
      lacc += cbn[bi] + znl[t] - 2.0f * S[t * R + bi];
    }
    zq4[(size_t)gt * 64 + lane] = cb4[(size_t)bi * 64 + lane];
  }
  if (lane == 0) wred2[wv] = lacc;
  __syncthreads();
  if (tid == 0)
    lossp[blockIdx.x] = wred2[0] + wred2[1] + wred2[2] + wred2[3];
}

// ---- pass B: counts / embed sums (streaming, reg-pipelined) ----
// grid = 1024 = 128 chunks x 8 col-groups of 32.  2048 tokens per chunk.
template <int K>
__global__ __launch_bounds__(256) void k_passB(
    const float* __restrict__ zre, const float* __restrict__ zim,
    const int* __restrict__ idxi,
    float* __restrict__ emb_ws, int* __restrict__ cnt_ws) {
  constexpr int PAD = 33;
  constexpr int TC  = 2048;
  __shared__ float eml[K * PAD];
  __shared__ int   cntl[K];
  const int tid = threadIdx.x;
  const int c   = blockIdx.x >> 3;
  const int g   = blockIdx.x & 7;
  for (int e = tid; e < K * PAD; e += 256) eml[e] = 0.0f;
  if (tid < K) cntl[tid] = 0;
  __syncthreads();
  const int wv  = tid >> 6, l = tid & 63;
  const int sub = l >> 3, cl = l & 7;           // 8 tokens x 8 lanes x float4
  const float* zsrc = (g < 4) ? zre : zim;
  const int jloc = (g & 3) * 32;
  const int tbase = c * TC + wv * 8 + sub;
  const bool docnt = (g == 0) && (cl == 0);
  // software pipeline: prefetch next iteration's idx + z while adding current
  int    id = idxi[tbase];
  float4 z  = *(const float4*)&zsrc[(size_t)tbase * LATD + jloc + cl * 4];
#pragma unroll 4
  for (int i = 0; i < TC / 32; ++i) {
    int    id_c = id;
    float4 z_c  = z;
    if (i + 1 < TC / 32) {
      int tn = tbase + (i + 1) * 32;
      id = idxi[tn];
      z  = *(const float4*)&zsrc[(size_t)tn * LATD + jloc + cl * 4];
    }
    float* rowp = &eml[id_c * PAD + cl * 4];
    atomicAdd(rowp + 0, z_c.x);
    atomicAdd(rowp + 1, z_c.y);
    atomicAdd(rowp + 2, z_c.z);
    atomicAdd(rowp + 3, z_c.w);
    if (docnt) atomicAdd(&cntl[id_c], 1);
  }
  __syncthreads();
  const int jglob = g * 32;
  for (int e = tid; e < K * 32; e += 256) {
    int k = e >> 5, c2 = e & 31;
    atomicAdd(&emb_ws[k * DIMD + jglob + c2], eml[k * PAD + c2]);
  }
  if (g == 0)
    for (int e = tid; e < K; e += 256) atomicAdd(&cnt_ws[e], cntl[e]);
}

// ---- finalize 1: cl_new, n sums, loss ----
__global__ __launch_bounds__(256) void k_fin1(
    float* __restrict__ ws, const float* __restrict__ clsi, const float* __restrict__ clmi,
    float* __restrict__ out_cl_syn, float* __restrict__ out_cl_sem, float* __restrict__ out_loss) {
  __shared__ float red[256];
  __shared__ float s1[64], s2[128];
  const int* wsi = (const int*)ws;
  int tid = threadIdx.x;
  float s = 0.0f;
  for (int i = tid; i < 16384; i += 256) s += ws[W_LOSSP_SYN + i];
  red[tid] = s;
  if (tid < 64) {
    float c  = (float)wsi[W_CNT_SYN + tid];
    float cl = clsi[tid] * 0.99f + 0.01f * c;
    out_cl_syn[tid] = cl; s1[tid] = cl;
  }
  if (tid < 128) {
    float c  = (float)wsi[W_CNT_SEM + tid];
    float cl = clmi[tid] * 0.99f + 0.01f * c;
    out_cl_sem[tid] = cl; s2[tid] = cl;
  }
  __syncthreads();
  for (int st = 128; st > 0; st >>= 1) {
    if (tid < st) red[tid] += red[tid + st];
    __syncthreads();
  }
  if (tid == 0) {
    float n1 = 0.0f; for (int i = 0; i < 64;  ++i) n1 += s1[i];
    float n2 = 0.0f; for (int i = 0; i < 128; ++i) n2 += s2[i];
    ws[W_N_SYN] = n1;
    ws[W_N_SEM] = n2;
    float denom = (float)N_TOK * 256.0f;
    *out_loss = 1.25f * red[0] / denom;
  }
}

// ---- finalize 2: avg_new, cb_new, adj_new ----
__global__ __launch_bounds__(256) void k_fin2(
    const float* __restrict__ ws,
    const float* __restrict__ avgs, const float* __restrict__ avgm,
    const float* __restrict__ adjs, const float* __restrict__ adjm,
    const float* __restrict__ clsi, const float* __restrict__ clmi,
    float* __restrict__ o_cb_syn, float* __restrict__ o_avg_syn, float* __restrict__ o_adj_syn,
    float* __restrict__ o_cb_sem, float* __restrict__ o_avg_sem, float* __restrict__ o_adj_sem) {
  const int* wsi = (const int*)ws;
  int e = blockIdx.x * 256 + threadIdx.x;
  if (e < 16384) {                       // syn avg/cb
    int k = e >> 8;
    float av = avgs[e] * 0.99f + 0.01f * ws[W_EMB_SYN + e];
    o_avg_syn[e] = av;
    float cnt = (float)wsi[W_CNT_SYN + k];
    float cl  = clsi[k] * 0.99f + 0.01f * cnt;
    float n   = ws[W_N_SYN];
    float cs  = (cl + 1e-6f) / (n + (float)(64 * 1e-6)) * n;
    o_cb_syn[e] = av / cs;
  } else if (e < 49152) {                // sem avg/cb
    int e2 = e - 16384;
    int k = e2 >> 8;
    float av = avgm[e2] * 0.99f + 0.01f * ws[W_EMB_SEM + e2];
    o_avg_sem[e2] = av;
    float cnt = (float)wsi[W_CNT_SEM + k];
    float cl  = clmi[k] * 0.99f + 0.01f * cnt;
    float n   = ws[W_N_SEM];
    float cs  = (cl + 1e-6f) / (n + (float)(128 * 1e-6)) * n;
    o_cb_sem[e2] = av / cs;
  } else if (e < 53248) {                // adj syn
    int a = e - 49152;
    float old = adjs[a];
    o_adj_syn[a] = wsi[W_MRK_SYN + a] ? old * 0.995f + 1.0f : old;
  } else if (e < 69632) {                // adj sem
    int a = e - 53248;
    float old = adjm[a];
    o_adj_sem[a] = wsi[W_MRK_SEM + a] ? old * 0.995f + 1.0f : old;
  }
}

extern "C" void kernel_launch(void* const* d_in, const int* in_sizes, int n_in,
                              void* d_out, int out_size, void* d_ws, size_t ws_size,
                              hipStream_t stream) {
  const float* zfre = (const float*)d_in[0];
  const float* zfim = (const float*)d_in[1];
  const float* zsre = (const float*)d_in[2];
  const float* zsim = (const float*)d_in[3];
  const float* cbs  = (const float*)d_in[4];
  const float* cbm  = (const float*)d_in[5];
  const float* Wsy  = (const float*)d_in[6];
  const float* bsy  = (const float*)d_in[7];
  const float* Wse  = (const float*)d_in[8];
  const float* bse  = (const float*)d_in[9];
  const float* clsi = (const float*)d_in[10];
  const float* avgs = (const float*)d_in[11];
  const float* clmi = (const float*)d_in[12];
  const float* avgm = (const float*)d_in[13];
  const float* adjs = (const float*)d_in[14];
  const float* adjm = (const float*)d_in[15];
  const int*   prvs = (const int*)d_in[16];
  const int*   prvm = (const int*)d_in[17];

  float* out = (float*)d_out;
  float* wsf = (float*)d_ws;
  int*   wsi = (int*)d_ws;
  _Float16* wsh = (_Float16*)d_ws;

  k_init<<<(W_ZERO_END - W_ZERO_BEG + 255) / 256, 256, 0, stream>>>(wsf);
  k_prep_pack<64><<<128, 256, 0, stream>>>(cbs, Wsy, wsh + 2 * W_PACK_SYN);
  k_prep_pack<128><<<256, 256, 0, stream>>>(cbm, Wse, wsh + 2 * W_PACK_SEM);
  k_prep_norm<<<192, 256, 0, stream>>>(cbs, cbm, wsf);

  k_passA<64><<<N_TOK / 32, 256, 0, stream>>>(
      zfre, zfim, wsh + 2 * W_PACK_SYN, wsf + W_CBN_SYN, cbs, bsy, adjs, prvs,
      out + OFF_ZQ_SYN, out + OFF_IDX_SYN, wsi + W_IDX_SYN, wsi + W_MRK_SYN,
      wsf + W_LOSSP_SYN);
  k_passA<128><<<N_TOK / 32, 256, 0, stream>>>(
      zsre, zsim, wsh + 2 * W_PACK_SEM, wsf + W_CBN_SEM, cbm, bse, adjm, prvm,
      out + OFF_ZQ_SEM, out + OFF_IDX_SEM, wsi + W_IDX_SEM, wsi + W_MRK_SEM,
      wsf + W_LOSSP_SEM);

  k_passB<64><<<1024, 256, 0, stream>>>(
      zfre, zfim, wsi + W_IDX_SYN, wsf + W_EMB_SYN, wsi + W_CNT_SYN);
  k_passB<128><<<1024, 256, 0, stream>>>(
      zsre, zsim, wsi + W_IDX_SEM, wsf + W_EMB_SEM, wsi + W_CNT_SEM);

  k_fin1<<<1, 256, 0, stream>>>(wsf, clsi, clmi,
      out + OFF_CL_SYN, out + OFF_CL_SEM, out + OFF_LOSS);
  k_fin2<<<272, 256, 0, stream>>>(wsf, avgs, avgm, adjs, adjm, clsi, clmi,
      out + OFF_CB_SYN, out + OFF_AVG_SYN, out + OFF_ADJ_SYN,
      out + OFF_CB_SEM, out + OFF_AVG_SEM, out + OFF_ADJ_SEM);
}

// Round 4
// 829.341 us; speedup vs baseline: 2.2165x; 1.4950x over previous
//
#include <hip/hip_runtime.h>

#define N_TOK 262144
#define LATD  128
#define DIMD  256

using f32x4  = __attribute__((ext_vector_type(4)))  float;
using f32x16 = __attribute__((ext_vector_type(16))) float;
using f16x8  = __attribute__((ext_vector_type(8)))  _Float16;

// ---------------- workspace layout (32-bit word offsets) ----------------
#define W_PACK_SYN 0         // 65536 f16 (32768 words): [kt][hi/lo][ct][lane][e]
#define W_PACK_SEM 32768     // 131072 f16 (65536 words)
#define W_CBN_SYN  98304     // 64  f32 ||cb||^2
#define W_CBN_SEM  98368     // 128 f32
#define W_IDX_SYN  98496     // 262144 i32
#define W_IDX_SEM  360640    // 262144 i32
#define W_CNT_SYN  622784    // 64  i32
#define W_CNT_SEM  622848    // 128 i32
#define W_EMB_SYN  622976    // 64x256 f32
#define W_EMB_SEM  639360    // 128x256 f32
#define W_MRK_SYN  672128    // 64x64 i32
#define W_MRK_SEM  676224    // 128x128 i32
#define W_N_SYN    692610    // f32
#define W_N_SEM    692611    // f32
#define W_LOSSP_SYN 692612   // 8192 f32 per-block loss partials
#define W_LOSSP_SEM 700804   // 8192 f32
#define W_ZERO_BEG 622784
#define W_ZERO_END 692612

// ---------------- output layout (float offsets) ----------------
#define OFF_ZQ_SYN  0LL
#define OFF_ZQ_SEM  67108864LL
#define OFF_LOSS    134217728LL
#define OFF_IDX_SYN 134217729LL
#define OFF_IDX_SEM 134479873LL
#define OFF_CB_SYN  134742017LL
#define OFF_CL_SYN  134758401LL
#define OFF_AVG_SYN 134758465LL
#define OFF_ADJ_SYN 134774849LL
#define OFF_CB_SEM  134778945LL
#define OFF_CL_SEM  134811713LL
#define OFF_AVG_SEM 134811841LL
#define OFF_ADJ_SEM 134844609LL

__device__ inline void gload16(const void* g, void* l) {
  __builtin_amdgcn_global_load_lds(
      (const __attribute__((address_space(1))) unsigned int*)g,
      (__attribute__((address_space(3))) unsigned int*)l, 16, 0, 0);
}

__global__ __launch_bounds__(256) void k_init(float* __restrict__ ws) {
  int idx = W_ZERO_BEG + blockIdx.x * 256 + threadIdx.x;
  if (idx < W_ZERO_END) ws[idx] = 0.0f;
}

// Pack Mt = [cb^T | W] into 32x32x16 f16 fragment order, hi + lo halves.
template <int K>
__global__ __launch_bounds__(256) void k_prep_pack(
    const float* __restrict__ cb, const float* __restrict__ W,
    _Float16* __restrict__ pack) {
  constexpr int R   = 2 * K;
  constexpr int NCT = R / 32;
  constexpr int PER_KT = NCT * 512;
  int t = blockIdx.x * 256 + threadIdx.x;   // < 16*PER_KT
  int kt = t / PER_KT;
  int r  = t - kt * PER_KT;
  int ct = r >> 9;
  int l  = (r >> 3) & 63;
  int e  = r & 7;
  int j   = kt * 16 + (l >> 5) * 8 + e;
  int col = ct * 32 + (l & 31);
  float x = (col < K) ? cb[col * DIMD + j] : W[j * K + (col - K)];
  _Float16 h = (_Float16)x;
  _Float16 lo = (_Float16)(x - (float)h);
  pack[(size_t)kt * 2 * PER_KT + r]          = h;
  pack[(size_t)kt * 2 * PER_KT + PER_KT + r] = lo;
}

// ||cb_k||^2.  grid = 192 blocks (64 syn + 128 sem), 256 threads.
__global__ __launch_bounds__(256) void k_prep_norm(
    const float* __restrict__ cbs, const float* __restrict__ cbm,
    float* __restrict__ ws) {
  __shared__ float red[256];
  int k = blockIdx.x;
  const float* src;
  float* dst;
  if (k < 64) { src = cbs + (size_t)k * DIMD; dst = ws + W_CBN_SYN + k; }
  else        { src = cbm + (size_t)(k - 64) * DIMD; dst = ws + W_CBN_SEM + (k - 64); }
  float v = src[threadIdx.x];
  red[threadIdx.x] = v * v;
  __syncthreads();
  for (int s = 128; s > 0; s >>= 1) {
    if (threadIdx.x < s) red[threadIdx.x] += red[threadIdx.x + s];
    __syncthreads();
  }
  if (threadIdx.x == 0) *dst = red[0];
}

// ---- pass A: split-f16 MFMA GEMM + softmax/argmin/zq + loss partials ----
template <int K>
__global__ __launch_bounds__(256) void k_passA(
    const float* __restrict__ zre, const float* __restrict__ zim,
    const _Float16* __restrict__ pack, const float* __restrict__ cbn,
    const float* __restrict__ cb,  const float* __restrict__ bvec,
    const float* __restrict__ adj, const int* __restrict__ prev,
    float* __restrict__ zq_out, float* __restrict__ idxf_out,
    int* __restrict__ idxi_ws, int* __restrict__ mark_ws,
    float* __restrict__ lossp) {
  constexpr int R   = 2 * K;           // 128 / 256
  constexpr int NCT = R / 32;          // 4 / 8
  constexpr int TB  = 32;              // tokens per block
  constexpr int NKT = 16;              // k-chunks of 16
  constexpr int PER_KT = NCT * 512;    // f16 per hi (or lo) chunk
  constexpr int BW  = 2 * PER_KT;      // f16 per staged chunk
  constexpr int NACC = NCT / 4;        // col-tiles per wave (1 or 2)
  __shared__ __align__(16) float smem[TB * 256 + BW / 2];  // A f32 tile + B f16 chunk
  __shared__ float znl[TB];
  __shared__ float wred2[4];

  const int tid  = threadIdx.x;
  const int lane = tid & 63;
  const int wv   = tid >> 6;
  const int t0   = blockIdx.x * TB;
  _Float16* Bp = (_Float16*)(smem + TB * 256);

  // ---- stage A tile (f32) via global_load_lds, source pre-swizzled ----
#pragma unroll
  for (int it = 0; it < 8; ++it) {
    int off16 = it * 256 + tid;        // 16B slot id, 64 slots per row
    int row = off16 >> 6;
    int s   = off16 & 63;
    int fidx = s ^ (row & 7);
    const float* g = (fidx < 32)
        ? (zre + (((size_t)(t0 + row)) << 7) + fidx * 4)
        : (zim + (((size_t)(t0 + row)) << 7) + (fidx - 32) * 4);
    gload16(g, (char*)smem + ((it * 256 + (tid & 192)) << 4));
  }
  // ---- stage B chunk kt=0 ----
  {
    const _Float16* src = pack;
#pragma unroll
    for (int i = 0; i < BW / 2048; ++i)
      gload16(src + (size_t)(i * 256 + tid) * 8,
              (char*)Bp + ((i * 256 + (tid & 192)) << 4));
  }

  const int row = lane & 31;
  const int kg  = lane >> 5;
  const int ct0 = wv * NACC;
  f32x16 acc[NACC];
#pragma unroll
  for (int c = 0; c < NACC; ++c)
#pragma unroll
    for (int r = 0; r < 16; ++r) acc[c][r] = 0.0f;
  float zn = 0.0f;                     // partial ||zf_row||^2 (this lane's k-slices)

  for (int kt = 0; kt < NKT; ++kt) {
    __syncthreads();                   // B(kt) staged (+A on kt=0); prev compute done
    int f0 = kt * 4 + kg * 2;
    f32x4 v0 = *(const f32x4*)&smem[row * 256 + ((f0)     ^ (row & 7)) * 4];
    f32x4 v1 = *(const f32x4*)&smem[row * 256 + ((f0 + 1) ^ (row & 7)) * 4];
    f16x8 Ah, Al;
#pragma unroll
    for (int e = 0; e < 4; ++e) {
      _Float16 h0 = (_Float16)v0[e];
      Ah[e] = h0;       Al[e] = (_Float16)(v0[e] - (float)h0);
      _Float16 h1 = (_Float16)v1[e];
      Ah[e + 4] = h1;   Al[e + 4] = (_Float16)(v1[e] - (float)h1);
      zn += v0[e] * v0[e];
      zn += v1[e] * v1[e];
    }
#pragma unroll
    for (int c = 0; c < NACC; ++c) {
      int ct = ct0 + c;
      f16x8 Bh = *(const f16x8*)(Bp + ((size_t)(ct) * 64 + lane) * 8);
      f16x8 Bl = *(const f16x8*)(Bp + ((size_t)(NCT + ct) * 64 + lane) * 8);
      acc[c] = __builtin_amdgcn_mfma_f32_32x32x16_f16(Ah, Bh, acc[c], 0, 0, 0);
      acc[c] = __builtin_amdgcn_mfma_f32_32x32x16_f16(Ah, Bl, acc[c], 0, 0, 0);
      acc[c] = __builtin_amdgcn_mfma_f32_32x32x16_f16(Al, Bh, acc[c], 0, 0, 0);
    }
    if (kt + 1 < NKT) {
      __syncthreads();                 // everyone done reading B(kt)
      const _Float16* src = pack + (size_t)(kt + 1) * BW;
#pragma unroll
      for (int i = 0; i < BW / 2048; ++i)
        gload16(src + (size_t)(i * 256 + tid) * 8,
                (char*)Bp + ((i * 256 + (tid & 192)) << 4));
    }
  }
  // full ||zf_row||^2: combine the two kg half-sums; wave 0 publishes
  {
    float znt = zn + __shfl_xor(zn, 32);
    if (wv == 0 && lane < 32) znl[lane] = znt;
  }
  __syncthreads();                     // compute done; A region reusable as S

  // ---- dump S[32][R] (f32) into A region ----
  float* S = smem;
#pragma unroll
  for (int c = 0; c < NACC; ++c) {
    int col = ct0 * 32 + c * 32 + (lane & 31);
#pragma unroll
    for (int r = 0; r < 16; ++r) {
      int rw = (r & 3) + 8 * (r >> 2) + 4 * kg;
      S[rw * R + col] = acc[c][r];
    }
  }
  __syncthreads();

  // ---- epilogue: one wave per token ----
  const float4* cb4 = (const float4*)cb;
  float4* zq4 = (float4*)zq_out;
  float lacc = 0.0f;
  for (int t = wv; t < TB; t += 4) {
    const int gt = t0 + t;
    const int pv = prev[gt];
    float bv; int bi;
    if (K == 64) {
      float lg = S[t * R + 64 + lane] + bvec[lane];
      float mx = lg;
#pragma unroll
      for (int off = 32; off; off >>= 1) mx = fmaxf(mx, __shfl_xor(mx, off));
      float e = __expf(lg - mx);
      float es = e;
#pragma unroll
      for (int off = 32; off; off >>= 1) es += __shfl_xor(es, off);
      float p  = e / es;
      float av = adj[pv * 64 + lane];
      float sg = 1.0f / (1.0f + __expf(-av));
      bv = cbn[lane] - 2.0f * S[t * R + lane] - 0.8f * sg - 2.0f * p;
      bi = lane;
    } else {
      float lg0 = S[t * R + 128 + lane] + bvec[lane];
      float lg1 = S[t * R + 192 + lane] + bvec[lane + 64];
      float mx = fmaxf(lg0, lg1);
#pragma unroll
      for (int off = 32; off; off >>= 1) mx = fmaxf(mx, __shfl_xor(mx, off));
      float e0 = __expf(lg0 - mx), e1 = __expf(lg1 - mx);
      float es = e0 + e1;
#pragma unroll
      for (int off = 32; off; off >>= 1) es += __shfl_xor(es, off);
      float a0 = adj[pv * 128 + lane], a1 = adj[pv * 128 + 64 + lane];
      float s0 = 1.0f / (1.0f + __expf(-a0));
      float s1 = 1.0f / (1.0f + __expf(-a1));
      float dv0 = cbn[lane]      - 2.0f * S[t * R + lane]      - 0.8f * s0 - 2.0f * (e0 / es);
      float dv1 = cbn[lane + 64] - 2.0f * S[t * R + 64 + lane] - 0.8f * s1 - 2.0f * (e1 / es);
      bv = dv0; bi = lane;
      if (dv1 < dv0) { bv = dv1; bi = lane + 64; }
    }
#pragma unroll
    for (int off = 32; off; off >>= 1) {
      float ov = __shfl_xor(bv, off);
      int   oi = __shfl_xor(bi, off);
      if (ov < bv || (ov == bv && oi < bi)) { bv = ov; bi = oi; }
    }
    if (lane == 0) {
      idxf_out[gt] = (float)bi;
      idxi_ws[gt]  = bi;
      mark_ws[pv * K + bi] = 1;
      // loss partial: ||cb_bi||^2 - 2*zf.cb_bi + ||zf||^2
      lacc += cbn[bi] + znl[t] - 2.0f * S[t * R + bi];
    }
    zq4[(size_t)gt * 64 + lane] = cb4[(size_t)bi * 64 + lane];
  }
  if (lane == 0) wred2[wv] = lacc;
  __syncthreads();
  if (tid == 0)
    lossp[blockIdx.x] = wred2[0] + wred2[1] + wred2[2] + wred2[3];
}

// ---- pass B: embed sums via one-hot MFMA (emb = P^T @ zf), counts via LDS ----
// grid = 256 chunks x 4 col-groups (64 cols each).  TPB=1024 tokens per block.
template <int K>
__global__ __launch_bounds__(256) void k_passB(
    const float* __restrict__ zre, const float* __restrict__ zim,
    const int* __restrict__ idxi,
    float* __restrict__ emb_ws, int* __restrict__ cnt_ws) {
  constexpr int TPB  = 1024;
  constexpr int NCT2 = (K == 64) ? 1 : 2;   // col-tiles per wave
  __shared__ int idxl[TPB];
  __shared__ int cntl[K];
  const int tid  = threadIdx.x;
  const int lane = tid & 63, wv = tid >> 6;
  const int chunk = blockIdx.x >> 2;        // 0..255
  const int cg    = blockIdx.x & 3;         // which 64 of the 256 cols
  const int tbase = chunk * TPB;

  if (tid < K) cntl[tid] = 0;
  __syncthreads();
  // stage idx; cg==0 blocks also histogram counts (1 LDS atomic per token)
#pragma unroll
  for (int i = 0; i < TPB / 256; ++i) {
    int id = idxi[tbase + i * 256 + tid];
    idxl[i * 256 + tid] = id;
    if (cg == 0) atomicAdd(&cntl[id], 1);
  }
  __syncthreads();
  if (cg == 0 && tid < K) atomicAdd(&cnt_ws[tid], cntl[tid]);

  // wave -> (row-tile, col-tile) assignment
  const int rt  = (K == 64) ? (wv & 1) : wv;
  const int ct0 = (K == 64) ? (wv >> 1) : 0;
  const int krow = rt * 32 + (lane & 31);
  const int esub = (lane >> 5) * 8;
  const float* zsrc = (cg < 2) ? zre : zim;
  const int cbase = (cg & 1) * 64;          // col base within this z tensor

  f32x16 acc[NCT2];
#pragma unroll
  for (int c = 0; c < NCT2; ++c)
#pragma unroll
    for (int r = 0; r < 16; ++r) acc[c][r] = 0.0f;

  const _Float16 oneh = (_Float16)1.0f, zeroh = (_Float16)0.0f;
  for (int s = 0; s < TPB / 16; ++s) {
    const int tloc = s * 16 + esub;
    // A-frag: one-hot P (rows = codebook entries, k = tokens)
    f16x8 Af;
#pragma unroll
    for (int e = 0; e < 8; ++e)
      Af[e] = (idxl[tloc + e] == krow) ? oneh : zeroh;
    // B-frag(s): z values (cols = features, k = tokens), f16 convert
#pragma unroll
    for (int c = 0; c < NCT2; ++c) {
      const float* zp = zsrc + (size_t)(tbase + tloc) * LATD
                        + cbase + (ct0 + c) * 32 + (lane & 31);
      f16x8 Bf;
#pragma unroll
      for (int e = 0; e < 8; ++e)
        Bf[e] = (_Float16)zp[(size_t)e * LATD];
      acc[c] = __builtin_amdgcn_mfma_f32_32x32x16_f16(Af, Bf, acc[c], 0, 0, 0);
    }
  }
  // flush: one global atomic per acc element
#pragma unroll
  for (int c = 0; c < NCT2; ++c)
#pragma unroll
    for (int r = 0; r < 16; ++r) {
      int row = rt * 32 + (r & 3) + 8 * (r >> 2) + 4 * (lane >> 5);
      int col = cg * 64 + (ct0 + c) * 32 + (lane & 31);
      atomicAdd(&emb_ws[row * DIMD + col], acc[c][r]);
    }
}

// ---- finalize 1: cl_new, n sums, loss ----
__global__ __launch_bounds__(256) void k_fin1(
    float* __restrict__ ws, const float* __restrict__ clsi, const float* __restrict__ clmi,
    float* __restrict__ out_cl_syn, float* __restrict__ out_cl_sem, float* __restrict__ out_loss) {
  __shared__ float red[256];
  __shared__ float s1[64], s2[128];
  const int* wsi = (const int*)ws;
  int tid = threadIdx.x;
  float s = 0.0f;
  for (int i = tid; i < 16384; i += 256) s += ws[W_LOSSP_SYN + i];
  red[tid] = s;
  if (tid < 64) {
    float c  = (float)wsi[W_CNT_SYN + tid];
    float cl = clsi[tid] * 0.99f + 0.01f * c;
    out_cl_syn[tid] = cl; s1[tid] = cl;
  }
  if (tid < 128) {
    float c  = (float)wsi[W_CNT_SEM + tid];
    float cl = clmi[tid] * 0.99f + 0.01f * c;
    out_cl_sem[tid] = cl; s2[tid] = cl;
  }
  __syncthreads();
  for (int st = 128; st > 0; st >>= 1) {
    if (tid < st) red[tid] += red[tid + st];
    __syncthreads();
  }
  if (tid == 0) {
    float n1 = 0.0f; for (int i = 0; i < 64;  ++i) n1 += s1[i];
    float n2 = 0.0f; for (int i = 0; i < 128; ++i) n2 += s2[i];
    ws[W_N_SYN] = n1;
    ws[W_N_SEM] = n2;
    float denom = (float)N_TOK * 256.0f;
    *out_loss = 1.25f * red[0] / denom;
  }
}

// ---- finalize 2: avg_new, cb_new, adj_new ----
__global__ __launch_bounds__(256) void k_fin2(
    const float* __restrict__ ws,
    const float* __restrict__ avgs, const float* __restrict__ avgm,
    const float* __restrict__ adjs, const float* __restrict__ adjm,
    const float* __restrict__ clsi, const float* __restrict__ clmi,
    float* __restrict__ o_cb_syn, float* __restrict__ o_avg_syn, float* __restrict__ o_adj_syn,
    float* __restrict__ o_cb_sem, float* __restrict__ o_avg_sem, float* __restrict__ o_adj_sem) {
  const int* wsi = (const int*)ws;
  int e = blockIdx.x * 256 + threadIdx.x;
  if (e < 16384) {                       // syn avg/cb
    int k = e >> 8;
    float av = avgs[e] * 0.99f + 0.01f * ws[W_EMB_SYN + e];
    o_avg_syn[e] = av;
    float cnt = (float)wsi[W_CNT_SYN + k];
    float cl  = clsi[k] * 0.99f + 0.01f * cnt;
    float n   = ws[W_N_SYN];
    float cs  = (cl + 1e-6f) / (n + (float)(64 * 1e-6)) * n;
    o_cb_syn[e] = av / cs;
  } else if (e < 49152) {                // sem avg/cb
    int e2 = e - 16384;
    int k = e2 >> 8;
    float av = avgm[e2] * 0.99f + 0.01f * ws[W_EMB_SEM + e2];
    o_avg_sem[e2] = av;
    float cnt = (float)wsi[W_CNT_SEM + k];
    float cl  = clmi[k] * 0.99f + 0.01f * cnt;
    float n   = ws[W_N_SEM];
    float cs  = (cl + 1e-6f) / (n + (float)(128 * 1e-6)) * n;
    o_cb_sem[e2] = av / cs;
  } else if (e < 53248) {                // adj syn
    int a = e - 49152;
    float old = adjs[a];
    o_adj_syn[a] = wsi[W_MRK_SYN + a] ? old * 0.995f + 1.0f : old;
  } else if (e < 69632) {                // adj sem
    int a = e - 53248;
    float old = adjm[a];
    o_adj_sem[a] = wsi[W_MRK_SEM + a] ? old * 0.995f + 1.0f : old;
  }
}

extern "C" void kernel_launch(void* const* d_in, const int* in_sizes, int n_in,
                              void* d_out, int out_size, void* d_ws, size_t ws_size,
                              hipStream_t stream) {
  const float* zfre = (const float*)d_in[0];
  const float* zfim = (const float*)d_in[1];
  const float* zsre = (const float*)d_in[2];
  const float* zsim = (const float*)d_in[3];
  const float* cbs  = (const float*)d_in[4];
  const float* cbm  = (const float*)d_in[5];
  const float* Wsy  = (const float*)d_in[6];
  const float* bsy  = (const float*)d_in[7];
  const float* Wse  = (const float*)d_in[8];
  const float* bse  = (const float*)d_in[9];
  const float* clsi = (const float*)d_in[10];
  const float* avgs = (const float*)d_in[11];
  const float* clmi = (const float*)d_in[12];
  const float* avgm = (const float*)d_in[13];
  const float* adjs = (const float*)d_in[14];
  const float* adjm = (const float*)d_in[15];
  const int*   prvs = (const int*)d_in[16];
  const int*   prvm = (const int*)d_in[17];

  float* out = (float*)d_out;
  float* wsf = (float*)d_ws;
  int*   wsi = (int*)d_ws;
  _Float16* wsh = (_Float16*)d_ws;

  k_init<<<(W_ZERO_END - W_ZERO_BEG + 255) / 256, 256, 0, stream>>>(wsf);
  k_prep_pack<64><<<128, 256, 0, stream>>>(cbs, Wsy, wsh + 2 * W_PACK_SYN);
  k_prep_pack<128><<<256, 256, 0, stream>>>(cbm, Wse, wsh + 2 * W_PACK_SEM);
  k_prep_norm<<<192, 256, 0, stream>>>(cbs, cbm, wsf);

  k_passA<64><<<N_TOK / 32, 256, 0, stream>>>(
      zfre, zfim, wsh + 2 * W_PACK_SYN, wsf + W_CBN_SYN, cbs, bsy, adjs, prvs,
      out + OFF_ZQ_SYN, out + OFF_IDX_SYN, wsi + W_IDX_SYN, wsi + W_MRK_SYN,
      wsf + W_LOSSP_SYN);
  k_passA<128><<<N_TOK / 32, 256, 0, stream>>>(
      zsre, zsim, wsh + 2 * W_PACK_SEM, wsf + W_CBN_SEM, cbm, bse, adjm, prvm,
      out + OFF_ZQ_SEM, out + OFF_IDX_SEM, wsi + W_IDX_SEM, wsi + W_MRK_SEM,
      wsf + W_LOSSP_SEM);

  k_passB<64><<<1024, 256, 0, stream>>>(
      zfre, zfim, wsi + W_IDX_SYN, wsf + W_EMB_SYN, wsi + W_CNT_SYN);
  k_passB<128><<<1024, 256, 0, stream>>>(
      zsre, zsim, wsi + W_IDX_SEM, wsf + W_EMB_SEM, wsi + W_CNT_SEM);

  k_fin1<<<1, 256, 0, stream>>>(wsf, clsi, clmi,
      out + OFF_CL_SYN, out + OFF_CL_SEM, out + OFF_LOSS);
  k_fin2<<<272, 256, 0, stream>>>(wsf, avgs, avgm, adjs, adjm, clsi, clmi,
      out + OFF_CB_SYN, out + OFF_AVG_SYN, out + OFF_ADJ_SYN,
      out + OFF_CB_SEM, out + OFF_AVG_SEM, out + OFF_ADJ_SEM);
}